// Round 14
// baseline (578.249 us; speedup 1.0000x reference)
//
#include <hip/hip_runtime.h>
#include <hip/hip_fp16.h>

// GCN, 7 layers: h = relu(Â (h W) + b), Â = D^-1/2 (A + I) D^-1/2.
// Round 14: (a) agg lanes vectorized — each lane gathers 4 half2 (16B int4)
// per edge; LPN 8/4/2. Cuts per-edge lane-instruction count ~2.5x (r13 showed
// agg issue-bound at VALUBusy 48% after padding fixed the fetch side).
// (b) matmul __launch_bounds__(256,1): r13 showed VGPR_Count=20 with acc[25]
// live -> compiler squeezed registers for occupancy; uncap so acc + pipelined
// X loads stay in registers.

static constexpr int NN = 100000;
static constexpr int NE = 1600000;
static constexpr int BKL = 9;                      // 512 nodes per bucket
static constexpr int NBUK = (NN + 511) >> BKL;     // 196 buckets
static constexpr int EPT = 8;                      // edges per thread (hist/A1)
static constexpr int EB = (NE + 2047) / 2048;      // 782 edge blocks

// ---------------- 1. bucket histogram (LDS only) ----------------

__global__ __launch_bounds__(256) void k_hist0(const int* __restrict__ col,
                                               int* __restrict__ counts) {
    __shared__ int lh[NBUK];
    for (int j = threadIdx.x; j < NBUK; j += 256) lh[j] = 0;
    __syncthreads();
    int base = blockIdx.x * 2048;
#pragma unroll
    for (int k = 0; k < EPT; ++k) {
        int e = base + k * 256 + threadIdx.x;
        if (e < NE) atomicAdd(&lh[col[e] >> BKL], 1);
    }
    __syncthreads();
    for (int j = threadIdx.x; j < NBUK; j += 256)
        counts[j * EB + blockIdx.x] = lh[j];  // bucket-major
}

// ---------------- 2a. per-bucket scan (196 parallel blocks) ----------------

__global__ __launch_bounds__(256) void k_scanA(int* __restrict__ counts,
                                               int* __restrict__ btot) {
    __shared__ int lds[256];
    const int b = blockIdx.x;
    const int t = threadIdx.x;
    int* c = counts + (size_t)b * EB;
    constexpr int PER = (EB + 255) / 256;  // 4
    int v[PER];
    int s = 0;
#pragma unroll
    for (int k = 0; k < PER; ++k) {
        int idx = t * PER + k;
        v[k] = (idx < EB) ? c[idx] : 0;
        s += v[k];
    }
    lds[t] = s;
    __syncthreads();
    for (int off = 1; off < 256; off <<= 1) {
        int u = (t >= off) ? lds[t - off] : 0;
        __syncthreads();
        lds[t] += u;
        __syncthreads();
    }
    int run = lds[t] - s;
#pragma unroll
    for (int k = 0; k < PER; ++k) {
        int idx = t * PER + k;
        if (idx < EB) { c[idx] = run; run += v[k]; }
    }
    if (t == 255) btot[b] = lds[255];
}

// ---------------- 2b. scan of 196 bucket totals -> bstart ----------------

__global__ void k_scanB(const int* __restrict__ btot, int* __restrict__ bstart) {
    __shared__ int lds[256];
    int t = threadIdx.x;
    int v = (t < NBUK) ? btot[t] : 0;
    lds[t] = v;
    __syncthreads();
    for (int off = 1; off < 256; off <<= 1) {
        int u = (t >= off) ? lds[t - off] : 0;
        __syncthreads();
        lds[t] += u;
        __syncthreads();
    }
    if (t < NBUK) bstart[t] = lds[t] - v;  // exclusive
    if (t == 0) bstart[NBUK] = NE;
}

// ---------------- 3. stage records, bucket-grouped (LDS cursors) ----------

__global__ __launch_bounds__(256) void k_A1(const int* __restrict__ row,
                                            const int* __restrict__ col,
                                            const float* __restrict__ ew,
                                            const int* __restrict__ counts,
                                            const int* __restrict__ bstart,
                                            int2* __restrict__ stg) {
    __shared__ int cur[NBUK];
    for (int j = threadIdx.x; j < NBUK; j += 256)
        cur[j] = bstart[j] + counts[j * EB + blockIdx.x];
    __syncthreads();
    int base = blockIdx.x * 2048;
#pragma unroll
    for (int k = 0; k < EPT; ++k) {
        int e = base + k * 256 + threadIdx.x;
        if (e < NE) {
            int c = col[e], r = row[e];
            int pos = atomicAdd(&cur[c >> BKL], 1);  // LDS atomic
            stg[pos] = make_int2(((c & 511) << 17) | r, __float_as_int(ew[e]));
        }
    }
}

// ---------------- 4. per-bucket degree -> dinv (plain stores) ----------

__global__ __launch_bounds__(256) void k_bdeg(const int* __restrict__ bstart,
                                              const int2* __restrict__ stg,
                                              float* __restrict__ dinv) {
    __shared__ float sdeg[512];
    const int b = blockIdx.x;
    for (int j = threadIdx.x; j < 512; j += 256) sdeg[j] = 0.0f;
    __syncthreads();
    const int s = bstart[b], e = bstart[b + 1];
    for (int p = s + threadIdx.x; p < e; p += 256) {
        int2 rec = stg[p];
        atomicAdd(&sdeg[rec.x >> 17], __int_as_float(rec.y));
    }
    __syncthreads();
    for (int j = threadIdx.x; j < 512; j += 256) {
        int idx = (b << BKL) + j;
        if (idx < NN) dinv[idx] = rsqrtf(sdeg[j] + 1.0f);  // +1 self-loop
    }
}

// ---------------- 5. per-bucket placement: offs + csw (LDS scan) ----------

__global__ __launch_bounds__(512) void k_place(const int* __restrict__ bstart,
                                               const int2* __restrict__ stg,
                                               const float* __restrict__ dinv,
                                               int* __restrict__ offs,
                                               int2* __restrict__ csw) {
    __shared__ int lcnt[512];
    __shared__ int cur[512];
    const int b = blockIdx.x;
    const int t = threadIdx.x;
    lcnt[t] = 0;
    __syncthreads();
    const int s = bstart[b], e = bstart[b + 1];
    for (int p = s + t; p < e; p += 512)
        atomicAdd(&lcnt[stg[p].x >> 17], 1);
    __syncthreads();
    int v = lcnt[t];
    for (int off = 1; off < 512; off <<= 1) {   // inclusive Hillis-Steele
        int u = (t >= off) ? lcnt[t - off] : 0;
        __syncthreads();
        lcnt[t] += u;
        __syncthreads();
    }
    int excl = lcnt[t] - v;
    int idx = (b << BKL) + t;
    if (idx <= NN) offs[idx] = s + excl;        // covers offs[NN] exactly once
    cur[t] = s + excl;
    __syncthreads();
    for (int p = s + t; p < e; p += 512) {
        int2 rec = stg[p];
        int cl = rec.x >> 17;
        int r = rec.x & 0x1FFFF;
        float nw = dinv[r] * __int_as_float(rec.y) * dinv[(b << BKL) + cl];
        int slot = atomicAdd(&cur[cl], 1);      // LDS atomic
        csw[slot] = make_int2(r, __float_as_int(nw));
    }
}

// ---------------- dense H = X * W (fp32 in, fp16 out, padded stride) -------
// blockIdx.y = output chunk (wave-uniform -> W on s_load path). (256,1):
// no VGPR cap, acc stays in registers and X loads can pipeline.

template <int FIN, int FOUT, int S, int NSPL>
__global__ __launch_bounds__(256, 1) void k_matmul(const float* __restrict__ X,
                                                   const float* __restrict__ W,
                                                   __half* __restrict__ H) {
    constexpr int FC = FOUT / NSPL;
    const int node = blockIdx.x * 256 + threadIdx.x;
    const int ch = blockIdx.y;           // SGPR by construction
    if (node >= NN) return;
    const float* xr = X + (size_t)node * FIN;
    float acc[FC];
#pragma unroll
    for (int j = 0; j < FC; ++j) acc[j] = 0.0f;

    constexpr int KV = (FIN % 4 == 0) ? 4 : 2;
    for (int k = 0; k < FIN; k += KV) {
        float xv[KV];
        if constexpr (KV == 4) *(float4*)xv = *(const float4*)(xr + k);
        else                   *(float2*)xv = *(const float2*)(xr + k);
#pragma unroll
        for (int kk = 0; kk < KV; ++kk)
#pragma unroll
            for (int j = 0; j < FC; ++j)
                acc[j] = fmaf(xv[kk], W[(k + kk) * FOUT + ch * FC + j], acc[j]);
    }
    __half* hr = H + (size_t)node * S + ch * FC;
#pragma unroll
    for (int j = 0; j < FC; ++j) hr[j] = __float2half_rn(acc[j]);
}

// final layer 10 -> 1 (fp32 H)
template <int FIN>
__global__ void k_matmul_1(const float* __restrict__ X, const float* __restrict__ W,
                           float* __restrict__ H) {
    int i = blockIdx.x * blockDim.x + threadIdx.x;
    if (i >= NN) return;
    const float* xr = X + (size_t)i * FIN;
    float acc = 0.0f;
#pragma unroll
    for (int k = 0; k < FIN; k += 2) {
        float2 xv = *(const float2*)(xr + k);
        acc = fmaf(xv.x, W[k], acc);
        acc = fmaf(xv.y, W[k + 1], acc);
    }
    H[i] = acc;
}

// ---------------- CSR pull aggregation + fused epilogue (fp16 H) ----------
// Lane handles 4 half2s (one 16B gather per edge). LPN = ceil-pow2 of
// (F/2)/4 lanes per node. Pad half2s are finite garbage (0xAA pattern),
// accumulated but never stored. csw records read nontemporal.

static __device__ __forceinline__ int2 nt_load2(const int2* p) {
    unsigned long long raw = __builtin_nontemporal_load((const unsigned long long*)p);
    return make_int2((int)(raw & 0xFFFFFFFFull), (int)(raw >> 32));
}

template <int F, int SH, int LPN, bool RELU>
__global__ __launch_bounds__(256) void k_agg2(const int* __restrict__ offs,
                                              const int2* __restrict__ csw,
                                              const __half2* __restrict__ H,
                                              const float* __restrict__ dinv,
                                              const float* __restrict__ b,
                                              float* __restrict__ O) {
    constexpr int R = F / 2;               // real half2 count per row
    int t = blockIdx.x * blockDim.x + threadIdx.x;
    int g = t / LPN;
    int f = t - g * LPN;
    if (g >= NN) return;
    const int q0 = 4 * f;                  // first half2 this lane owns
    if (q0 >= R) return;                   // fully-pad lane: idle
    int p = offs[g];
    const int pe = offs[g + 1];
    const int pl = pe - 1;

    float2 acc[4];
#pragma unroll
    for (int c = 0; c < 4; ++c) acc[c] = make_float2(0.f, 0.f);

    for (; p < pe; p += 4) {
        int2 e[4];
#pragma unroll
        for (int i = 0; i < 4; ++i) e[i] = nt_load2(csw + min(p + i, pl));
        __half2 h[4][4];
#pragma unroll
        for (int i = 0; i < 4; ++i)
            *(int4*)h[i] = *(const int4*)(H + (size_t)e[i].x * SH + q0);
#pragma unroll
        for (int i = 0; i < 4; ++i) {
            float w = (p + i < pe) ? __int_as_float(e[i].y) : 0.0f;
#pragma unroll
            for (int c = 0; c < 4; ++c) {
                acc[c].x = fmaf(__low2float(h[i][c]), w, acc[c].x);
                acc[c].y = fmaf(__high2float(h[i][c]), w, acc[c].y);
            }
        }
    }

    float di = dinv[g];
    float d2 = di * di;
    __half2 hs[4];
    *(int4*)hs = *(const int4*)(H + (size_t)g * SH + q0);
    float* orow = O + (size_t)g * F + 2 * q0;
#pragma unroll
    for (int c = 0; c < 4; ++c) {
        if (q0 + c < R) {
            float vx = acc[c].x + fmaf(__low2float(hs[c]), d2, b[2 * (q0 + c)]);
            float vy = acc[c].y + fmaf(__high2float(hs[c]), d2, b[2 * (q0 + c) + 1]);
            if (RELU) { vx = fmaxf(vx, 0.f); vy = fmaxf(vy, 0.f); }
            *(float2*)(orow + 2 * c) = make_float2(vx, vy);
        }
    }
}

// F=1 aggregation (final layer, fp32 H): one thread per node, predicated 4-wide.
__global__ void k_agg1(const int* __restrict__ offs, const int2* __restrict__ csw,
                       const float* __restrict__ H, const float* __restrict__ dinv,
                       const float* __restrict__ b, float* __restrict__ O) {
    int g = blockIdx.x * blockDim.x + threadIdx.x;
    if (g >= NN) return;
    int p = offs[g];
    const int pe = offs[g + 1];
    const int pl = pe - 1;
    float a0 = 0.f, a1 = 0.f, a2 = 0.f, a3 = 0.f;
    for (; p < pe; p += 4) {
        int2 e0 = nt_load2(csw + min(p, pl)),     e1 = nt_load2(csw + min(p + 1, pl));
        int2 e2 = nt_load2(csw + min(p + 2, pl)), e3 = nt_load2(csw + min(p + 3, pl));
        float w0 = (p < pe)     ? __int_as_float(e0.y) : 0.f;
        float w1 = (p + 1 < pe) ? __int_as_float(e1.y) : 0.f;
        float w2 = (p + 2 < pe) ? __int_as_float(e2.y) : 0.f;
        float w3 = (p + 3 < pe) ? __int_as_float(e3.y) : 0.f;
        a0 = fmaf(H[e0.x], w0, a0);
        a1 = fmaf(H[e1.x], w1, a1);
        a2 = fmaf(H[e2.x], w2, a2);
        a3 = fmaf(H[e3.x], w3, a3);
    }
    float di = dinv[g];
    O[g] = ((a0 + a1) + (a2 + a3)) + fmaf(H[g], di * di, b[0]);
}

// ---------------- launch ----------------

static inline size_t alignup(size_t x) { return (x + 255) & ~(size_t)255; }

extern "C" void kernel_launch(void* const* d_in, const int* in_sizes, int n_in,
                              void* d_out, int out_size, void* d_ws, size_t ws_size,
                              hipStream_t stream) {
    const float* x  = (const float*)d_in[0];
    const int*   ei = (const int*)d_in[1];
    const float* ew = (const float*)d_in[2];
    const float* Wp[7];
    const float* Bp[7];
    for (int l = 0; l < 7; ++l) {
        Wp[l] = (const float*)d_in[3 + 2 * l];
        Bp[l] = (const float*)d_in[4 + 2 * l];
    }
    const int* row = ei;       // source
    const int* col = ei + NE;  // destination

    // workspace carve (~84 MB); Hb padded to 64 halfs/row (12.8 MB)
    char* ws = (char*)d_ws;
    float* dinv  = (float*)ws;  ws += alignup((size_t)NN * 4);
    char*  Hb    = ws;          ws += alignup((size_t)NN * 64 * 2);
    float* Aa    = (float*)ws;  ws += alignup((size_t)NN * 50 * 4);
    float* Ab    = (float*)ws;  ws += alignup((size_t)NN * 50 * 4);
    int*   offs  = (int*)ws;    ws += alignup((size_t)(NN + 1) * 4);
    int*   counts= (int*)ws;    ws += alignup((size_t)NBUK * EB * 4);
    int*   btot  = (int*)ws;    ws += alignup((size_t)NBUK * 4);
    int*   bstart= (int*)ws;    ws += alignup((size_t)(NBUK + 1) * 4);
    int2*  stg   = (int2*)ws;   ws += alignup((size_t)NE * 8);
    int2*  csw   = (int2*)ws;   ws += alignup((size_t)NE * 8);

    const int gN = (NN + 255) / 256;

    // CSR build — no global atomics, no single-block O(N) scans
    k_hist0<<<EB, 256, 0, stream>>>(col, counts);
    k_scanA<<<NBUK, 256, 0, stream>>>(counts, btot);
    k_scanB<<<1, 256, 0, stream>>>(btot, bstart);
    k_A1<<<EB, 256, 0, stream>>>(row, col, ew, counts, bstart, stg);
    k_bdeg<<<NBUK, 256, 0, stream>>>(bstart, stg, dinv);
    k_place<<<NBUK, 512, 0, stream>>>(bstart, stg, dinv, offs, csw);

#define LAYER(FIN, FOUT, S, NSPL, LPN, RELU, XIN, OUT, LIDX)                                \
    do {                                                                                    \
        k_matmul<FIN, FOUT, S, NSPL><<<dim3(gN, NSPL), 256, 0, stream>>>(                   \
            (XIN), Wp[LIDX], (__half*)Hb);                                                  \
        k_agg2<FOUT, (S) / 2, LPN, RELU>                                                    \
            <<<((size_t)NN * (LPN) + 255) / 256, 256, 0, stream>>>(                         \
                offs, csw, (const __half2*)Hb, dinv, Bp[LIDX], (OUT));                      \
    } while (0)

    LAYER(128, 50, 64, 2, 8, true, x,  Aa, 0);
    LAYER(50,  50, 64, 2, 8, true, Aa, Ab, 1);
    LAYER(50,  30, 32, 2, 4, true, Ab, Aa, 2);
    LAYER(30,  30, 32, 2, 4, true, Aa, Ab, 3);
    LAYER(30,  10, 16, 1, 2, true, Ab, Aa, 4);
    LAYER(10,  10, 16, 1, 2, true, Aa, Ab, 5);
#undef LAYER

    // layer 7: 10 -> 1, no relu, fp32 H
    k_matmul_1<10><<<gN, 256, 0, stream>>>(Ab, Wp[6], (float*)Hb);
    k_agg1<<<gN, 256, 0, stream>>>(offs, csw, (const float*)Hb, dinv, Bp[6],
                                   (float*)d_out);
}

// Round 15
// 470.252 us; speedup vs baseline: 1.2297x; 1.2297x over previous
//
#include <hip/hip_runtime.h>
#include <hip/hip_fp16.h>

// GCN, 7 layers: h = relu(Â (h W) + b), Â = D^-1/2 (A + I) D^-1/2.
// Round 15: break the matmul serial-load chain. (a) Activations stored fp16
// by the agg epilogue (pow2 strides) -> layers 2..7 matmuls read half the
// bytes with all chunk loads issued upfront (<=7 int4s in flight). (b) L1
// matmul (fp32 x, FIN=128): explicit 2-stage double-buffered pipeline, 4
// float4 loads in flight per thread. (c) agg2 writes halve (fp16 out).

static constexpr int NN = 100000;
static constexpr int NE = 1600000;
static constexpr int BKL = 9;                      // 512 nodes per bucket
static constexpr int NBUK = (NN + 511) >> BKL;     // 196 buckets
static constexpr int EPT = 8;                      // edges per thread (hist/A1)
static constexpr int EB = (NE + 2047) / 2048;      // 782 edge blocks

// ---------------- 1. bucket histogram (LDS only) ----------------

__global__ __launch_bounds__(256) void k_hist0(const int* __restrict__ col,
                                               int* __restrict__ counts) {
    __shared__ int lh[NBUK];
    for (int j = threadIdx.x; j < NBUK; j += 256) lh[j] = 0;
    __syncthreads();
    int base = blockIdx.x * 2048;
#pragma unroll
    for (int k = 0; k < EPT; ++k) {
        int e = base + k * 256 + threadIdx.x;
        if (e < NE) atomicAdd(&lh[col[e] >> BKL], 1);
    }
    __syncthreads();
    for (int j = threadIdx.x; j < NBUK; j += 256)
        counts[j * EB + blockIdx.x] = lh[j];  // bucket-major
}

// ---------------- 2a. per-bucket scan (196 parallel blocks) ----------------

__global__ __launch_bounds__(256) void k_scanA(int* __restrict__ counts,
                                               int* __restrict__ btot) {
    __shared__ int lds[256];
    const int b = blockIdx.x;
    const int t = threadIdx.x;
    int* c = counts + (size_t)b * EB;
    constexpr int PER = (EB + 255) / 256;  // 4
    int v[PER];
    int s = 0;
#pragma unroll
    for (int k = 0; k < PER; ++k) {
        int idx = t * PER + k;
        v[k] = (idx < EB) ? c[idx] : 0;
        s += v[k];
    }
    lds[t] = s;
    __syncthreads();
    for (int off = 1; off < 256; off <<= 1) {
        int u = (t >= off) ? lds[t - off] : 0;
        __syncthreads();
        lds[t] += u;
        __syncthreads();
    }
    int run = lds[t] - s;
#pragma unroll
    for (int k = 0; k < PER; ++k) {
        int idx = t * PER + k;
        if (idx < EB) { c[idx] = run; run += v[k]; }
    }
    if (t == 255) btot[b] = lds[255];
}

// ---------------- 2b. scan of 196 bucket totals -> bstart ----------------

__global__ void k_scanB(const int* __restrict__ btot, int* __restrict__ bstart) {
    __shared__ int lds[256];
    int t = threadIdx.x;
    int v = (t < NBUK) ? btot[t] : 0;
    lds[t] = v;
    __syncthreads();
    for (int off = 1; off < 256; off <<= 1) {
        int u = (t >= off) ? lds[t - off] : 0;
        __syncthreads();
        lds[t] += u;
        __syncthreads();
    }
    if (t < NBUK) bstart[t] = lds[t] - v;  // exclusive
    if (t == 0) bstart[NBUK] = NE;
}

// ---------------- 3. stage records, bucket-grouped (LDS cursors) ----------

__global__ __launch_bounds__(256) void k_A1(const int* __restrict__ row,
                                            const int* __restrict__ col,
                                            const float* __restrict__ ew,
                                            const int* __restrict__ counts,
                                            const int* __restrict__ bstart,
                                            int2* __restrict__ stg) {
    __shared__ int cur[NBUK];
    for (int j = threadIdx.x; j < NBUK; j += 256)
        cur[j] = bstart[j] + counts[j * EB + blockIdx.x];
    __syncthreads();
    int base = blockIdx.x * 2048;
#pragma unroll
    for (int k = 0; k < EPT; ++k) {
        int e = base + k * 256 + threadIdx.x;
        if (e < NE) {
            int c = col[e], r = row[e];
            int pos = atomicAdd(&cur[c >> BKL], 1);  // LDS atomic
            stg[pos] = make_int2(((c & 511) << 17) | r, __float_as_int(ew[e]));
        }
    }
}

// ---------------- 4. per-bucket degree -> dinv (plain stores) ----------

__global__ __launch_bounds__(256) void k_bdeg(const int* __restrict__ bstart,
                                              const int2* __restrict__ stg,
                                              float* __restrict__ dinv) {
    __shared__ float sdeg[512];
    const int b = blockIdx.x;
    for (int j = threadIdx.x; j < 512; j += 256) sdeg[j] = 0.0f;
    __syncthreads();
    const int s = bstart[b], e = bstart[b + 1];
    for (int p = s + threadIdx.x; p < e; p += 256) {
        int2 rec = stg[p];
        atomicAdd(&sdeg[rec.x >> 17], __int_as_float(rec.y));
    }
    __syncthreads();
    for (int j = threadIdx.x; j < 512; j += 256) {
        int idx = (b << BKL) + j;
        if (idx < NN) dinv[idx] = rsqrtf(sdeg[j] + 1.0f);  // +1 self-loop
    }
}

// ---------------- 5. per-bucket placement: offs + csw (LDS scan) ----------

__global__ __launch_bounds__(512) void k_place(const int* __restrict__ bstart,
                                               const int2* __restrict__ stg,
                                               const float* __restrict__ dinv,
                                               int* __restrict__ offs,
                                               int2* __restrict__ csw) {
    __shared__ int lcnt[512];
    __shared__ int cur[512];
    const int b = blockIdx.x;
    const int t = threadIdx.x;
    lcnt[t] = 0;
    __syncthreads();
    const int s = bstart[b], e = bstart[b + 1];
    for (int p = s + t; p < e; p += 512)
        atomicAdd(&lcnt[stg[p].x >> 17], 1);
    __syncthreads();
    int v = lcnt[t];
    for (int off = 1; off < 512; off <<= 1) {   // inclusive Hillis-Steele
        int u = (t >= off) ? lcnt[t - off] : 0;
        __syncthreads();
        lcnt[t] += u;
        __syncthreads();
    }
    int excl = lcnt[t] - v;
    int idx = (b << BKL) + t;
    if (idx <= NN) offs[idx] = s + excl;        // covers offs[NN] exactly once
    cur[t] = s + excl;
    __syncthreads();
    for (int p = s + t; p < e; p += 512) {
        int2 rec = stg[p];
        int cl = rec.x >> 17;
        int r = rec.x & 0x1FFFF;
        float nw = dinv[r] * __int_as_float(rec.y) * dinv[(b << BKL) + cl];
        int slot = atomicAdd(&cur[cl], 1);      // LDS atomic
        csw[slot] = make_int2(r, __float_as_int(nw));
    }
}

// ---------------- dense H = X * W, fp32 X (layer 1 only) ----------------
// blockIdx.y = output chunk (wave-uniform -> W on s_load path). Explicit
// 2-stage pipeline: double-buffered groups of 4 float4s, 4 loads in flight
// while 400 FMAs retire.

template <int FIN, int FOUT, int S, int NSPL>
__global__ __launch_bounds__(256, 2) void k_matmul_f(const float* __restrict__ X,
                                                     const float* __restrict__ W,
                                                     __half* __restrict__ H) {
    constexpr int FC = FOUT / NSPL;
    constexpr int NG = FIN / 16;               // groups of 16 floats
    const int node = blockIdx.x * 256 + threadIdx.x;
    const int ch = blockIdx.y;                 // SGPR by construction
    if (node >= NN) return;
    const float* xr = X + (size_t)node * FIN;
    float acc[FC];
#pragma unroll
    for (int j = 0; j < FC; ++j) acc[j] = 0.0f;

    float4 buf[2][4];
#pragma unroll
    for (int g = 0; g < 4; ++g) buf[0][g] = *(const float4*)(xr + 4 * g);
#pragma unroll
    for (int grp = 0; grp < NG; ++grp) {
        const int cur = grp & 1;
        if (grp + 1 < NG) {
#pragma unroll
            for (int g = 0; g < 4; ++g)
                buf[cur ^ 1][g] = *(const float4*)(xr + (grp + 1) * 16 + 4 * g);
        }
#pragma unroll
        for (int g = 0; g < 4; ++g)
#pragma unroll
            for (int kk = 0; kk < 4; ++kk) {
                float xv = ((const float*)&buf[cur][g])[kk];
                const float* wrow = W + (grp * 16 + 4 * g + kk) * FOUT + ch * FC;
#pragma unroll
                for (int j = 0; j < FC; ++j) acc[j] = fmaf(xv, wrow[j], acc[j]);
            }
    }
    __half* hr = H + (size_t)node * S + ch * FC;
#pragma unroll
    for (int j = 0; j < FC; ++j) hr[j] = __float2half_rn(acc[j]);
}

// ---------------- dense H = X * W, fp16 X (layers 2..6) ----------------
// All chunk loads issued upfront (<=7 independent int4s in flight), then
// pure FMA. Pad halfs beyond FIN are loaded but never used (bounded kk).

template <int FIN, int SX, int FOUT, int S, int NSPL>
__global__ __launch_bounds__(256, 2) void k_matmul_h(const __half* __restrict__ X,
                                                     const float* __restrict__ W,
                                                     __half* __restrict__ H) {
    constexpr int FC = FOUT / NSPL;
    constexpr int NCH = (FIN + 7) / 8;
    const int node = blockIdx.x * 256 + threadIdx.x;
    const int ch = blockIdx.y;                 // SGPR by construction
    if (node >= NN) return;
    const __half* xr = X + (size_t)node * SX;
    int4 raw[NCH];
#pragma unroll
    for (int c = 0; c < NCH; ++c) raw[c] = *(const int4*)(xr + 8 * c);
    float acc[FC];
#pragma unroll
    for (int j = 0; j < FC; ++j) acc[j] = 0.0f;
#pragma unroll
    for (int c = 0; c < NCH; ++c) {
        const __half2* hp = (const __half2*)&raw[c];
        const int lim = (FIN - 8 * c < 8) ? FIN - 8 * c : 8;  // folds post-unroll
#pragma unroll
        for (int kk = 0; kk < 8; ++kk) {
            if (kk < lim) {
                __half2 pair = hp[kk >> 1];
                float xv = (kk & 1) ? __high2float(pair) : __low2float(pair);
                const float* wrow = W + (8 * c + kk) * FOUT + ch * FC;
#pragma unroll
                for (int j = 0; j < FC; ++j) acc[j] = fmaf(xv, wrow[j], acc[j]);
            }
        }
    }
    __half* hr = H + (size_t)node * S + ch * FC;
#pragma unroll
    for (int j = 0; j < FC; ++j) hr[j] = __float2half_rn(acc[j]);
}

// layer 7: 10 -> 1, fp16 X (stride 16), fp32 H out
__global__ void k_matmul_1h(const __half* __restrict__ X, const float* __restrict__ W,
                            float* __restrict__ H) {
    int i = blockIdx.x * blockDim.x + threadIdx.x;
    if (i >= NN) return;
    const __half* xr = X + (size_t)i * 16;
    int4 r0 = *(const int4*)xr;                  // halfs 0..7
    __half2 r1 = *(const __half2*)(xr + 8);      // halfs 8,9
    const __half2* hp = (const __half2*)&r0;
    float acc = 0.0f;
#pragma unroll
    for (int q = 0; q < 4; ++q) {
        acc = fmaf(__low2float(hp[q]), W[2 * q], acc);
        acc = fmaf(__high2float(hp[q]), W[2 * q + 1], acc);
    }
    acc = fmaf(__low2float(r1), W[8], acc);
    acc = fmaf(__high2float(r1), W[9], acc);
    H[i] = acc;
}

// ---------------- CSR pull aggregation + fused epilogue (fp16 H) ----------
// Lane handles 4 half2s (one 16B gather per edge). Output stored fp16 at
// stride SA halfs (the next layer's X). csw records read nontemporal.

static __device__ __forceinline__ int2 nt_load2(const int2* p) {
    unsigned long long raw = __builtin_nontemporal_load((const unsigned long long*)p);
    return make_int2((int)(raw & 0xFFFFFFFFull), (int)(raw >> 32));
}

template <int F, int SH, int SA, int LPN, bool RELU>
__global__ __launch_bounds__(256) void k_agg2(const int* __restrict__ offs,
                                              const int2* __restrict__ csw,
                                              const __half2* __restrict__ H,
                                              const float* __restrict__ dinv,
                                              const float* __restrict__ b,
                                              __half* __restrict__ O) {
    constexpr int R = F / 2;               // real half2 count per row
    int t = blockIdx.x * blockDim.x + threadIdx.x;
    int g = t / LPN;
    int f = t - g * LPN;
    if (g >= NN) return;
    const int q0 = 4 * f;                  // first half2 this lane owns
    if (q0 >= R) return;                   // fully-pad lane: idle
    int p = offs[g];
    const int pe = offs[g + 1];
    const int pl = pe - 1;

    float2 acc[4];
#pragma unroll
    for (int c = 0; c < 4; ++c) acc[c] = make_float2(0.f, 0.f);

    for (; p < pe; p += 4) {
        int2 e[4];
#pragma unroll
        for (int i = 0; i < 4; ++i) e[i] = nt_load2(csw + min(p + i, pl));
        __half2 h[4][4];
#pragma unroll
        for (int i = 0; i < 4; ++i)
            *(int4*)h[i] = *(const int4*)(H + (size_t)e[i].x * SH + q0);
#pragma unroll
        for (int i = 0; i < 4; ++i) {
            float w = (p + i < pe) ? __int_as_float(e[i].y) : 0.0f;
#pragma unroll
            for (int c = 0; c < 4; ++c) {
                acc[c].x = fmaf(__low2float(h[i][c]), w, acc[c].x);
                acc[c].y = fmaf(__high2float(h[i][c]), w, acc[c].y);
            }
        }
    }

    float di = dinv[g];
    float d2 = di * di;
    __half2 hs[4];
    *(int4*)hs = *(const int4*)(H + (size_t)g * SH + q0);
    __half2* orow = (__half2*)(O + (size_t)g * SA) + q0;
#pragma unroll
    for (int c = 0; c < 4; ++c) {
        if (q0 + c < R) {
            float vx = acc[c].x + fmaf(__low2float(hs[c]), d2, b[2 * (q0 + c)]);
            float vy = acc[c].y + fmaf(__high2float(hs[c]), d2, b[2 * (q0 + c) + 1]);
            if (RELU) { vx = fmaxf(vx, 0.f); vy = fmaxf(vy, 0.f); }
            orow[c] = __floats2half2_rn(vx, vy);
        }
    }
}

// F=1 aggregation (final layer, fp32 H): one thread per node, predicated 4-wide.
__global__ void k_agg1(const int* __restrict__ offs, const int2* __restrict__ csw,
                       const float* __restrict__ H, const float* __restrict__ dinv,
                       const float* __restrict__ b, float* __restrict__ O) {
    int g = blockIdx.x * blockDim.x + threadIdx.x;
    if (g >= NN) return;
    int p = offs[g];
    const int pe = offs[g + 1];
    const int pl = pe - 1;
    float a0 = 0.f, a1 = 0.f, a2 = 0.f, a3 = 0.f;
    for (; p < pe; p += 4) {
        int2 e0 = nt_load2(csw + min(p, pl)),     e1 = nt_load2(csw + min(p + 1, pl));
        int2 e2 = nt_load2(csw + min(p + 2, pl)), e3 = nt_load2(csw + min(p + 3, pl));
        float w0 = (p < pe)     ? __int_as_float(e0.y) : 0.f;
        float w1 = (p + 1 < pe) ? __int_as_float(e1.y) : 0.f;
        float w2 = (p + 2 < pe) ? __int_as_float(e2.y) : 0.f;
        float w3 = (p + 3 < pe) ? __int_as_float(e3.y) : 0.f;
        a0 = fmaf(H[e0.x], w0, a0);
        a1 = fmaf(H[e1.x], w1, a1);
        a2 = fmaf(H[e2.x], w2, a2);
        a3 = fmaf(H[e3.x], w3, a3);
    }
    float di = dinv[g];
    O[g] = ((a0 + a1) + (a2 + a3)) + fmaf(H[g], di * di, b[0]);
}

// ---------------- launch ----------------

static inline size_t alignup(size_t x) { return (x + 255) & ~(size_t)255; }

extern "C" void kernel_launch(void* const* d_in, const int* in_sizes, int n_in,
                              void* d_out, int out_size, void* d_ws, size_t ws_size,
                              hipStream_t stream) {
    const float* x  = (const float*)d_in[0];
    const int*   ei = (const int*)d_in[1];
    const float* ew = (const float*)d_in[2];
    const float* Wp[7];
    const float* Bp[7];
    for (int l = 0; l < 7; ++l) {
        Wp[l] = (const float*)d_in[3 + 2 * l];
        Bp[l] = (const float*)d_in[4 + 2 * l];
    }
    const int* row = ei;       // source
    const int* col = ei + NE;  // destination

    // workspace carve (~70 MB); Hb/Aa/Ab fp16, stride <= 64 halfs
    char* ws = (char*)d_ws;
    float* dinv  = (float*)ws;  ws += alignup((size_t)NN * 4);
    char*  Hb    = ws;          ws += alignup((size_t)NN * 64 * 2);
    char*  Aa    = ws;          ws += alignup((size_t)NN * 64 * 2);
    char*  Ab    = ws;          ws += alignup((size_t)NN * 64 * 2);
    int*   offs  = (int*)ws;    ws += alignup((size_t)(NN + 1) * 4);
    int*   counts= (int*)ws;    ws += alignup((size_t)NBUK * EB * 4);
    int*   btot  = (int*)ws;    ws += alignup((size_t)NBUK * 4);
    int*   bstart= (int*)ws;    ws += alignup((size_t)(NBUK + 1) * 4);
    int2*  stg   = (int2*)ws;   ws += alignup((size_t)NE * 8);
    int2*  csw   = (int2*)ws;   ws += alignup((size_t)NE * 8);

    const int gN = (NN + 255) / 256;

    // CSR build — no global atomics, no single-block O(N) scans
    k_hist0<<<EB, 256, 0, stream>>>(col, counts);
    k_scanA<<<NBUK, 256, 0, stream>>>(counts, btot);
    k_scanB<<<1, 256, 0, stream>>>(btot, bstart);
    k_A1<<<EB, 256, 0, stream>>>(row, col, ew, counts, bstart, stg);
    k_bdeg<<<NBUK, 256, 0, stream>>>(bstart, stg, dinv);
    k_place<<<NBUK, 512, 0, stream>>>(bstart, stg, dinv, offs, csw);

#define AGG(FOUT, S, LPN, RELU, OUT, LIDX)                                                  \
    k_agg2<FOUT, (S) / 2, S, LPN, RELU>                                                     \
        <<<((size_t)NN * (LPN) + 255) / 256, 256, 0, stream>>>(                             \
            offs, csw, (const __half2*)Hb, dinv, Bp[LIDX], (__half*)(OUT))

    // layer 1: fp32 x input
    k_matmul_f<128, 50, 64, 2><<<dim3(gN, 2), 256, 0, stream>>>(x, Wp[0], (__half*)Hb);
    AGG(50, 64, 8, true, Aa, 0);
    // layers 2..6: fp16 activations in
    k_matmul_h<50, 64, 50, 64, 2><<<dim3(gN, 2), 256, 0, stream>>>((const __half*)Aa, Wp[1], (__half*)Hb);
    AGG(50, 64, 8, true, Ab, 1);
    k_matmul_h<50, 64, 30, 32, 2><<<dim3(gN, 2), 256, 0, stream>>>((const __half*)Ab, Wp[2], (__half*)Hb);
    AGG(30, 32, 4, true, Aa, 2);
    k_matmul_h<30, 32, 30, 32, 2><<<dim3(gN, 2), 256, 0, stream>>>((const __half*)Aa, Wp[3], (__half*)Hb);
    AGG(30, 32, 4, true, Ab, 3);
    k_matmul_h<30, 32, 10, 16, 1><<<dim3(gN, 1), 256, 0, stream>>>((const __half*)Ab, Wp[4], (__half*)Hb);
    AGG(10, 16, 2, true, Aa, 4);
    k_matmul_h<10, 16, 10, 16, 1><<<dim3(gN, 1), 256, 0, stream>>>((const __half*)Aa, Wp[5], (__half*)Hb);
    AGG(10, 16, 2, true, Ab, 5);
#undef AGG

    // layer 7: 10 -> 1, no relu, fp32 H, fp32 output
    k_matmul_1h<<<gN, 256, 0, stream>>>((const __half*)Ab, Wp[6], (float*)Hb);
    k_agg1<<<gN, 256, 0, stream>>>(offs, csw, (const float*)Hb, dinv, Bp[6],
                                   (float*)d_out);
}